// Round 4
// baseline (622.551 us; speedup 1.0000x reference)
//
#include <hip/hip_runtime.h>
#include <hip/hip_bf16.h>
#include <stdint.h>

#define BN 4
#define CN 128
#define HN 96
#define WN 96
#define HW (HN*WN)
#define OCN 128
#define OFFC 18
#define EPSV 1e-6f
#define TILE 32

__device__ __forceinline__ float lo16(uint32_t u) {
  union { uint32_t i; float f; } v; v.i = u << 16; return v.f;
}
__device__ __forceinline__ float hi16(uint32_t u) {
  union { uint32_t i; float f; } v; v.i = u & 0xffff0000u; return v.f;
}
__device__ __forceinline__ uint16_t f2b(float f) {
  union { float f; uint32_t i; } u; u.f = f;
  uint32_t r = u.i + 0x7fffu + ((u.i >> 16) & 1u);   // RNE
  return (uint16_t)(r >> 16);
}

// Fully fused: offsets-conv + deform-conv + LN + dw/pw/silu + add.
// Inputs fp32 (round-1 evidence: bf16 reinterpretation NaNs).
// OUTPUT fp32 (round-3 evidence: bf16-packed write gave absmax==7.31 with
// zero tail == max|ref| over untouched half; reference output dtype is f32).
__global__ __launch_bounds__(256)
void k_fused(const float* __restrict__ x,
             const float* __restrict__ w_off, const float* __restrict__ b_off,
             const float* __restrict__ w_def, const float* __restrict__ b_def,
             const float* __restrict__ ln_w, const float* __restrict__ ln_b,
             const float* __restrict__ w_dw, const float* __restrict__ b_dw,
             const float* __restrict__ w_pw, const float* __restrict__ b_pw,
             float* __restrict__ out) {
  // warena: phase O = w_off bf16 [kk][c][18] (20736 u16); later = wl [c][130]
  __shared__ uint16_t warena[20736];
  __shared__ float buf[CN][TILE];       // dw-out / samples / x1
  __shared__ float offl[OFFC][TILE];    // offsets tile (built in-block)
  __shared__ float mu[TILE], rs[TILE];

  int bid = blockIdx.x;
  int wt = bid % 3;
  int h  = (bid / 3) % HN;
  int b  = bid / (3 * HN);
  int w0 = wt * TILE;
  int t = (int)threadIdx.x;
  int p = t & 31, cg = t >> 5;          // pixel, channel-group (16 ch each)
  int xbase = b * CN * HW;

  // ---- phase O1: stage w_off transposed -> warena[(kk*128+c)*18 + j], init offl
  for (int i = t; i < OFFC * CN * 9; i += 256) {
    int j = i / (CN * 9), r = i - j * (CN * 9);
    int c = r / 9, kk = r - c * 9;
    warena[(kk * CN + c) * OFFC + j] = f2b(w_off[i]);
  }
  for (int i = t; i < OFFC * TILE; i += 256)
    offl[i / TILE][i & 31] = b_off[i / TILE];
  __syncthreads();

  // ---- phase O2: offsets conv partials (this thread: pixel p, channels cg*16..+16)
  {
    float accj[OFFC];
    #pragma unroll
    for (int j = 0; j < OFFC; ++j) accj[j] = 0.f;
    #pragma unroll 1
    for (int kk = 0; kk < 9; ++kk) {
      int ky = kk / 3, kx = kk - 3 * (kk / 3);
      int y = h + ky - 1, xx = w0 + p + kx - 1;
      bool ok = (y >= 0) & (y < HN) & (xx >= 0) & (xx < WN);
      const float* xp = x + xbase + (cg * 16) * HW + (ok ? y * WN + xx : 0);
      float msk = ok ? 1.f : 0.f;
      #pragma unroll
      for (int cl = 0; cl < 16; ++cl) {
        float xv = msk * xp[cl * HW];
        const uint16_t* wrow = &warena[(kk * CN + cg * 16 + cl) * OFFC];
        #pragma unroll
        for (int jh = 0; jh < 9; ++jh) {
          uint32_t u = *(const uint32_t*)&wrow[2 * jh];
          accj[2 * jh]     += lo16(u) * xv;
          accj[2 * jh + 1] += hi16(u) * xv;
        }
      }
    }
    // barriered 8-group reduction into offl
    for (int g = 0; g < 8; ++g) {
      if (cg == g) {
        #pragma unroll
        for (int j = 0; j < OFFC; ++j) offl[j][p] += accj[j];
      }
      __syncthreads();
    }
  }
  // offl now holds the 18x32 offsets tile; warena free for reuse.

  // ---- phase 1a: depthwise 3x3 + residual x -> buf[c][p]
  {
    int xw = w0 + p;
    for (int i = 0; i < 16; ++i) {
      int c = cg + (i << 3);
      const float* xc = x + xbase + c * HW;
      float a = b_dw[c];
      #pragma unroll
      for (int ky = 0; ky < 3; ++ky) {
        int y = h + ky - 1;
        if (y < 0 || y >= HN) continue;
        #pragma unroll
        for (int kx = 0; kx < 3; ++kx) {
          int xx = xw + kx - 1;
          if (xx < 0 || xx >= WN) continue;
          a += xc[y * WN + xx] * w_dw[c * 9 + ky * 3 + kx];
        }
      }
      a += xc[h * WN + xw];             // + x residual (pw input)
      buf[c][p] = a;
    }
  }
  // ---- phase 1b: w_pw -> warena as wl[c*130+oc]
  for (int e = t; e < OCN * CN; e += 256) {
    int oc = e >> 7, c = e & 127;
    warena[c * 130 + oc] = f2b(w_pw[e]);
  }
  __syncthreads();

  // ---- phase 1c: pointwise 1x1 + SiLU -> acc4 (registers)
  int m = t & 63, half = t >> 6, hp = half * 8;
  int oc0 = 2 * m;
  float acc4[2][8], acc1[2][8];
  {
    float bb0 = b_pw[oc0], bb1 = b_pw[oc0 + 1];
    #pragma unroll
    for (int ii = 0; ii < 8; ++ii) { acc4[0][ii] = bb0; acc4[1][ii] = bb1; }
    for (int c = 0; c < CN; ++c) {
      uint32_t wv = *(const uint32_t*)&warena[c * 130 + oc0];
      float wv0 = lo16(wv), wv1 = hi16(wv);
      const float4 sa = *(const float4*)&buf[c][hp];
      const float4 sb = *(const float4*)&buf[c][hp + 4];
      float s[8] = {sa.x, sa.y, sa.z, sa.w, sb.x, sb.y, sb.z, sb.w};
      #pragma unroll
      for (int ii = 0; ii < 8; ++ii) {
        acc4[0][ii] += wv0 * s[ii];
        acc4[1][ii] += wv1 * s[ii];
      }
    }
    #pragma unroll
    for (int ii = 0; ii < 8; ++ii) {
      float v0 = acc4[0][ii]; acc4[0][ii] = v0 / (1.f + __expf(-v0));
      float v1 = acc4[1][ii]; acc4[1][ii] = v1 / (1.f + __expf(-v1));
    }
    float bd0 = b_def[oc0], bd1 = b_def[oc0 + 1];
    #pragma unroll
    for (int ii = 0; ii < 8; ++ii) { acc1[0][ii] = bd0; acc1[1][ii] = bd1; }
  }
  __syncthreads();

  // ---- phases 2..10: deform conv, one kernel tap k at a time
  for (int k = 0; k < 9; ++k) {
    // stage w_def[:,:,k] transposed -> wl
    for (int e = t; e < OCN * CN; e += 256) {
      int oc = e >> 7, c = e & 127;
      warena[c * 130 + oc] = f2b(w_def[(oc * CN + c) * 9 + k]);
    }
    // gather bilinear samples -> buf[c][p]
    {
      int ky = k / 3, kx = k - 3 * (k / 3);
      float dy = offl[2 * k][p], dx = offl[2 * k + 1][p];
      float ys = (float)(h - 1 + ky) + dy;
      float xs = (float)(w0 + p - 1 + kx) + dx;
      float y0f = floorf(ys), x0f = floorf(xs);
      float fy = ys - y0f, fx = xs - x0f;
      int y0 = (int)y0f, x0 = (int)x0f;
      float w00 = (1.f - fy) * (1.f - fx), w01 = (1.f - fy) * fx;
      float w10 = fy * (1.f - fx),         w11 = fy * fx;
      bool yok0 = (y0 >= 0) & (y0 < HN), yok1 = (y0 + 1 >= 0) & (y0 + 1 < HN);
      bool xok0 = (x0 >= 0) & (x0 < WN), xok1 = (x0 + 1 >= 0) & (x0 + 1 < WN);
      int i00 = y0 * WN + x0;
      if (!(yok0 & xok0)) w00 = 0.f;
      if (!(yok0 & xok1)) w01 = 0.f;
      if (!(yok1 & xok0)) w10 = 0.f;
      if (!(yok1 & xok1)) w11 = 0.f;
      int c00 = (yok0 & xok0) ? i00 : 0;
      int c01 = (yok0 & xok1) ? i00 + 1 : 0;
      int c10 = (yok1 & xok0) ? i00 + WN : 0;
      int c11 = (yok1 & xok1) ? i00 + WN + 1 : 0;
      for (int i = 0; i < 16; ++i) {
        int c = cg + (i << 3);
        const float* xc = x + xbase + c * HW;
        float a = w00 * xc[c00] + w01 * xc[c01]
                + w10 * xc[c10] + w11 * xc[c11];
        buf[c][p] = a;
      }
    }
    __syncthreads();
    // accumulate: acc1[oc][p] += w_def[oc,c,k] * samp[c][p]
    for (int c = 0; c < CN; ++c) {
      uint32_t wv = *(const uint32_t*)&warena[c * 130 + oc0];
      float wv0 = lo16(wv), wv1 = hi16(wv);
      const float4 sa = *(const float4*)&buf[c][hp];
      const float4 sb = *(const float4*)&buf[c][hp + 4];
      float s[8] = {sa.x, sa.y, sa.z, sa.w, sb.x, sb.y, sb.z, sb.w};
      #pragma unroll
      for (int ii = 0; ii < 8; ++ii) {
        acc1[0][ii] += wv0 * s[ii];
        acc1[1][ii] += wv1 * s[ii];
      }
    }
    __syncthreads();
  }

  // ---- phase 11: LayerNorm over channels
  #pragma unroll
  for (int ii = 0; ii < 8; ++ii) {
    buf[oc0][hp + ii]     = acc1[0][ii];
    buf[oc0 + 1][hp + ii] = acc1[1][ii];
  }
  __syncthreads();
  if (t < TILE) {
    float s1 = 0.f, s2 = 0.f;
    for (int oc = 0; oc < OCN; ++oc) { float v = buf[oc][t]; s1 += v; s2 += v * v; }
    float mean = s1 * (1.f / OCN);
    float var  = s2 * (1.f / OCN) - mean * mean;
    mu[t] = mean;
    rs[t] = rsqrtf(var + EPSV);
  }
  __syncthreads();

  // ---- final: out = LN(x1) + silu(pw)  (fp32 output!)
  {
    #pragma unroll
    for (int q = 0; q < 2; ++q) {
      int oc = oc0 + q;
      float lw = ln_w[oc], lb = ln_b[oc];
      float res[8];
      #pragma unroll
      for (int ii = 0; ii < 8; ++ii) {
        int pp = hp + ii;
        res[ii] = (acc1[q][ii] - mu[pp]) * rs[pp] * lw + lb + acc4[q][ii];
      }
      float* op = &out[((size_t)(b * OCN + oc) * HN + h) * WN + w0 + hp];
      *(float4*)(op)     = make_float4(res[0], res[1], res[2], res[3]);
      *(float4*)(op + 4) = make_float4(res[4], res[5], res[6], res[7]);
    }
  }
}

extern "C" void kernel_launch(void* const* d_in, const int* in_sizes, int n_in,
                              void* d_out, int out_size, void* d_ws, size_t ws_size,
                              hipStream_t stream) {
  const float* x     = (const float*)d_in[0];
  const float* w_off = (const float*)d_in[1];
  const float* b_off = (const float*)d_in[2];
  const float* w_def = (const float*)d_in[3];
  const float* b_def = (const float*)d_in[4];
  const float* ln_w  = (const float*)d_in[5];
  const float* ln_b  = (const float*)d_in[6];
  const float* w_dw  = (const float*)d_in[7];
  const float* b_dw  = (const float*)d_in[8];
  const float* w_pw  = (const float*)d_in[9];
  const float* b_pw  = (const float*)d_in[10];
  float* out = (float*)d_out;

  hipLaunchKernelGGL(k_fused, dim3(BN * HN * 3), dim3(256), 0, stream,
                     x, w_off, b_off, w_def, b_def, ln_w, ln_b,
                     w_dw, b_dw, w_pw, b_pw, out);
}

// Round 5
// 244.849 us; speedup vs baseline: 2.5426x; 2.5426x over previous
//
#include <hip/hip_runtime.h>
#include <hip/hip_bf16.h>
#include <stdint.h>

#define BN 4
#define CN 128
#define HN 96
#define WN 96
#define HW (HN*WN)
#define OCN 128
#define OFFC 18
#define EPSV 1e-6f

typedef __attribute__((ext_vector_type(8))) short bf16x8;
typedef __attribute__((ext_vector_type(4))) float f32x4;

__device__ __forceinline__ float bb2f(uint16_t b) {
  union { uint32_t i; float f; } u; u.i = ((uint32_t)b) << 16; return u.f;
}
__device__ __forceinline__ uint16_t f2b(float f) {
  union { float f; uint32_t i; } u; u.f = f;
  uint32_t r = u.i + 0x7fffu + ((u.i >> 16) & 1u);   // RNE
  return (uint16_t)(r >> 16);
}
__device__ __forceinline__ uint32_t pk2(float a, float b) {
  return (uint32_t)f2b(a) | ((uint32_t)f2b(b) << 16);
}
// LDS chunk swizzle: XOR 16B-chunk index with row low bits (T2-style)
__device__ __forceinline__ int swz(int row, int c) { return c ^ ((row & 7) << 3); }

// Pre-transposed bf16 weights (written by k_prep every launch; deterministic).
__device__ __align__(16) uint16_t g_def[9 * 128 * 128];   // [k][oc][c]
__device__ __align__(16) uint16_t g_pw[128 * 128];        // [oc][c]
__device__ __align__(16) uint16_t g_off[32 * 1152];       // [j(pad32)][kk*128+c], rows 18..31 zero

__global__ __launch_bounds__(256)
void k_prep(const float* __restrict__ w_def, const float* __restrict__ w_pw,
            const float* __restrict__ w_off) {
  int i = blockIdx.x * 256 + threadIdx.x;
  if (i < 147456) {                       // 9*128*128
    int k = i >> 14, rem = i & 16383, oc = rem >> 7, c = rem & 127;
    g_def[i] = f2b(w_def[((oc << 7) + c) * 9 + k]);
  } else if (i < 147456 + 16384) {
    int j = i - 147456;
    g_pw[j] = f2b(w_pw[j]);
  } else if (i < 147456 + 16384 + 36864) {
    int j = i - 163840;
    int row = j / 1152, col = j - row * 1152;
    int kk = col >> 7, c = col & 127;
    g_off[j] = (row < OFFC) ? f2b(w_off[((row << 7) + c) * 9 + kk]) : (uint16_t)0;
  }
}

__global__ __launch_bounds__(256, 3)
void k_fused(const float* __restrict__ x,
             const float* __restrict__ b_off, const float* __restrict__ b_def,
             const float* __restrict__ ln_w, const float* __restrict__ ln_b,
             const float* __restrict__ w_dw, const float* __restrict__ b_dw,
             const float* __restrict__ b_pw, float* __restrict__ out) {
  // xT: [ky 0..2][i 0..33][c 0..127] bf16, chunk-swizzled. First 4096 reused as sampT[32][128].
  __shared__ __align__(16) uint16_t xT[3 * 34 * 128];
  __shared__ __align__(16) uint16_t dwT[32 * 128];
  __shared__ float offl[OFFC][32];
  __shared__ float red1[4][32], red2[4][32];
  __shared__ float muv[32], rsv[32];

  int bid = blockIdx.x;
  int wid = (bid & 7) * 144 + (bid >> 3);     // XCD-chunked swizzle (1152 = 8*144)
  int wt = wid % 3;
  int h  = (wid / 3) % HN;
  int b  = wid / (3 * HN);
  int w0 = wt * 32;

  int t = (int)threadIdx.x;
  int l = t & 63, w = t >> 6;                 // lane, wave
  int g = l >> 4, fr = l & 15;                // k-group, fragment row/col
  int p = t & 31, cg = t >> 5;                // gather mapping: pixel, channel-group(16)

  // ================= phase A: stage x patch -> xT (bf16, zero-padded) ========
  {
    for (int rep = 0; rep < 15; ++rep) {
      int e = t + 256 * rep;                  // 0..3839
      int q = e % 10, pair = e / 10;          // pair in [0,384)
      int c = pair & 127, ky = pair >> 7;
      int y = h - 1 + ky;
      int col4 = w0 - 4 + 4 * q;
      float v[4];
      bool yok = (y >= 0) & (y < HN);
      if (yok && col4 >= 0 && col4 + 3 < WN) {
        float4 f = *(const float4*)&x[(((b * CN + c) * HN) + y) * WN + col4];
        v[0] = f.x; v[1] = f.y; v[2] = f.z; v[3] = f.w;
      } else if (yok) {
        #pragma unroll
        for (int e4 = 0; e4 < 4; ++e4) {
          int col = col4 + e4;
          v[e4] = (col >= 0 && col < WN) ? x[(((b * CN + c) * HN) + y) * WN + col] : 0.f;
        }
      } else {
        v[0] = v[1] = v[2] = v[3] = 0.f;
      }
      #pragma unroll
      for (int e4 = 0; e4 < 4; ++e4) {
        int i = 4 * q - 3 + e4;
        if (i >= 0 && i < 34)
          xT[((ky * 34 + i) << 7) + swz(i, c)] = f2b(v[e4]);
      }
    }
  }
  __syncthreads();

  // ================= phase B1: offsets conv as MFMA (M=32pad, N=32, K=1152) ==
  {
    int toc = w >> 1, tp = w & 1;
    f32x4 aco = {0.f, 0.f, 0.f, 0.f};
    #pragma unroll
    for (int ks = 0; ks < 36; ++ks) {
      int kk = ks >> 2;
      int ky = kk / 3, kx = kk - 3 * ky;
      int cb = ((ks & 3) << 5) + (g << 3);
      int i = fr + (tp << 4) + kx;
      bf16x8 a = *(const bf16x8*)&g_off[(toc * 16 + fr) * 1152 + (ks << 5) + (g << 3)];
      bf16x8 bb = *(const bf16x8*)&xT[((ky * 34 + i) << 7) + swz(i, cb)];
      aco = __builtin_amdgcn_mfma_f32_16x16x32_bf16(a, bb, aco, 0, 0, 0);
    }
    #pragma unroll
    for (int reg = 0; reg < 4; ++reg) {
      int j = toc * 16 + g * 4 + reg;
      if (j < OFFC) offl[j][(tp << 4) + fr] = aco[reg] + b_off[j];
    }
  }

  // ================= phase B2: depthwise 3x3 + residual -> dwT (bf16) ========
  {
    float a[16];
    #pragma unroll
    for (int cl = 0; cl < 16; ++cl) {
      int c = cg * 16 + cl;
      float acc = b_dw[c];
      #pragma unroll
      for (int ky = 0; ky < 3; ++ky) {
        #pragma unroll
        for (int kx = 0; kx < 3; ++kx) {
          int i = p + kx;
          acc += bb2f(xT[((ky * 34 + i) << 7) + swz(i, c)]) * w_dw[c * 9 + ky * 3 + kx];
        }
      }
      acc += bb2f(xT[((34 + p + 1) << 7) + swz(p + 1, c)]);   // + x residual
      a[cl] = acc;
    }
    #pragma unroll
    for (int m = 0; m < 2; ++m) {
      uint4 u = { pk2(a[8*m+0], a[8*m+1]), pk2(a[8*m+2], a[8*m+3]),
                  pk2(a[8*m+4], a[8*m+5]), pk2(a[8*m+6], a[8*m+7]) };
      *(uint4*)&dwT[(p << 7) + swz(p, cg * 16 + 8 * m)] = u;
    }
  }
  __syncthreads();

  // ================= phase C: pointwise 1x1 MFMA + SiLU ======================
  f32x4 a4[2][2];
  #pragma unroll
  for (int q1 = 0; q1 < 2; ++q1)
    #pragma unroll
    for (int q2 = 0; q2 < 2; ++q2) a4[q1][q2] = (f32x4){0.f, 0.f, 0.f, 0.f};
  {
    #pragma unroll
    for (int ks = 0; ks < 4; ++ks) {
      int kb = (ks << 5) + (g << 3);
      bf16x8 a0 = *(const bf16x8*)&g_pw[(32 * w + fr) * 128 + kb];
      bf16x8 a1 = *(const bf16x8*)&g_pw[(32 * w + 16 + fr) * 128 + kb];
      #pragma unroll
      for (int tp2 = 0; tp2 < 2; ++tp2) {
        int pp = (tp2 << 4) + fr;
        bf16x8 bb = *(const bf16x8*)&dwT[(pp << 7) + swz(pp, kb)];
        a4[0][tp2] = __builtin_amdgcn_mfma_f32_16x16x32_bf16(a0, bb, a4[0][tp2], 0, 0, 0);
        a4[1][tp2] = __builtin_amdgcn_mfma_f32_16x16x32_bf16(a1, bb, a4[1][tp2], 0, 0, 0);
      }
    }
    #pragma unroll
    for (int toc2 = 0; toc2 < 2; ++toc2)
      #pragma unroll
      for (int tp2 = 0; tp2 < 2; ++tp2)
        #pragma unroll
        for (int reg = 0; reg < 4; ++reg) {
          int oc = 32 * w + 16 * toc2 + 4 * g + reg;
          float v = a4[toc2][tp2][reg] + b_pw[oc];
          a4[toc2][tp2][reg] = v / (1.f + __expf(-v));
        }
  }

  // ================= phase D: 9 deform taps (gather -> sampT -> MFMA) ========
  f32x4 ac1[2][2];
  #pragma unroll
  for (int q1 = 0; q1 < 2; ++q1)
    #pragma unroll
    for (int q2 = 0; q2 < 2; ++q2) ac1[q1][q2] = (f32x4){0.f, 0.f, 0.f, 0.f};

  uint16_t* sampT = xT;   // alias: xT dead after phase B
  #pragma unroll 1
  for (int k = 0; k < 9; ++k) {
    // ---- gather bilinear samples (thread = pixel p, channels cg*16..+15)
    {
      int ky = k / 3, kx = k - 3 * ky;
      float dy = offl[2 * k][p], dx = offl[2 * k + 1][p];
      float ys = (float)(h - 1 + ky) + dy;
      float xs = (float)(w0 + p - 1 + kx) + dx;
      float y0f = floorf(ys), x0f = floorf(xs);
      float fy = ys - y0f, fx = xs - x0f;
      int y0 = (int)y0f, x0 = (int)x0f;
      float w00 = (1.f - fy) * (1.f - fx), w01 = (1.f - fy) * fx;
      float w10 = fy * (1.f - fx),         w11 = fy * fx;
      bool yok0 = (y0 >= 0) & (y0 < HN), yok1 = (y0 + 1 >= 0) & (y0 + 1 < HN);
      bool xok0 = (x0 >= 0) & (x0 < WN), xok1 = (x0 + 1 >= 0) & (x0 + 1 < WN);
      int i00 = y0 * WN + x0;
      if (!(yok0 & xok0)) w00 = 0.f;
      if (!(yok0 & xok1)) w01 = 0.f;
      if (!(yok1 & xok0)) w10 = 0.f;
      if (!(yok1 & xok1)) w11 = 0.f;
      int c00 = (yok0 & xok0) ? i00 : 0;
      int c01 = (yok0 & xok1) ? i00 + 1 : 0;
      int c10 = (yok1 & xok0) ? i00 + WN : 0;
      int c11 = (yok1 & xok1) ? i00 + WN + 1 : 0;
      float smp[16];
      const float* xc = x + (b * CN + cg * 16) * HW;
      #pragma unroll
      for (int cl = 0; cl < 16; ++cl) {
        smp[cl] = w00 * xc[c00] + w01 * xc[c01] + w10 * xc[c10] + w11 * xc[c11];
        xc += HW;
      }
      #pragma unroll
      for (int m = 0; m < 2; ++m) {
        uint4 u = { pk2(smp[8*m+0], smp[8*m+1]), pk2(smp[8*m+2], smp[8*m+3]),
                    pk2(smp[8*m+4], smp[8*m+5]), pk2(smp[8*m+6], smp[8*m+7]) };
        *(uint4*)&sampT[(p << 7) + swz(p, cg * 16 + 8 * m)] = u;
      }
    }
    __syncthreads();
    // ---- MFMA accumulate: ac1 += w_def[k] x samp
    {
      const uint16_t* gdk = g_def + (k << 14);
      #pragma unroll
      for (int ks = 0; ks < 4; ++ks) {
        int kb = (ks << 5) + (g << 3);
        bf16x8 a0 = *(const bf16x8*)&gdk[(32 * w + fr) * 128 + kb];
        bf16x8 a1 = *(const bf16x8*)&gdk[(32 * w + 16 + fr) * 128 + kb];
        #pragma unroll
        for (int tp2 = 0; tp2 < 2; ++tp2) {
          int pp = (tp2 << 4) + fr;
          bf16x8 bb = *(const bf16x8*)&sampT[(pp << 7) + swz(pp, kb)];
          ac1[0][tp2] = __builtin_amdgcn_mfma_f32_16x16x32_bf16(a0, bb, ac1[0][tp2], 0, 0, 0);
          ac1[1][tp2] = __builtin_amdgcn_mfma_f32_16x16x32_bf16(a1, bb, ac1[1][tp2], 0, 0, 0);
        }
      }
    }
    __syncthreads();
  }

  // ================= phase E: bias + LayerNorm + add + store =================
  #pragma unroll
  for (int toc2 = 0; toc2 < 2; ++toc2)
    #pragma unroll
    for (int tp2 = 0; tp2 < 2; ++tp2)
      #pragma unroll
      for (int reg = 0; reg < 4; ++reg) {
        int oc = 32 * w + 16 * toc2 + 4 * g + reg;
        ac1[toc2][tp2][reg] += b_def[oc];
      }
  // per-pixel sums over this wave's 32 oc
  {
    float s1[2], s2[2];
    #pragma unroll
    for (int tp2 = 0; tp2 < 2; ++tp2) {
      float a = 0.f, q = 0.f;
      #pragma unroll
      for (int toc2 = 0; toc2 < 2; ++toc2)
        #pragma unroll
        for (int reg = 0; reg < 4; ++reg) {
          float v = ac1[toc2][tp2][reg];
          a += v; q += v * v;
        }
      a += __shfl_xor(a, 16); a += __shfl_xor(a, 32);
      q += __shfl_xor(q, 16); q += __shfl_xor(q, 32);
      s1[tp2] = a; s2[tp2] = q;
    }
    if (l < 16) {
      red1[w][l] = s1[0]; red1[w][l + 16] = s1[1];
      red2[w][l] = s2[0]; red2[w][l + 16] = s2[1];
    }
  }
  __syncthreads();
  if (t < 32) {
    float m = (red1[0][t] + red1[1][t] + red1[2][t] + red1[3][t]) * (1.f / 128.f);
    float q = (red2[0][t] + red2[1][t] + red2[2][t] + red2[3][t]) * (1.f / 128.f) - m * m;
    muv[t] = m;
    rsv[t] = rsqrtf(q + EPSV);
  }
  __syncthreads();
  {
    #pragma unroll
    for (int toc2 = 0; toc2 < 2; ++toc2)
      #pragma unroll
      for (int tp2 = 0; tp2 < 2; ++tp2) {
        int pp = (tp2 << 4) + fr;
        float mm = muv[pp], rr = rsv[pp];
        #pragma unroll
        for (int reg = 0; reg < 4; ++reg) {
          int oc = 32 * w + 16 * toc2 + 4 * g + reg;
          float v = (ac1[toc2][tp2][reg] - mm) * rr * ln_w[oc] + ln_b[oc]
                    + a4[toc2][tp2][reg];
          out[((size_t)(b * OCN + oc) * HN + h) * WN + w0 + pp] = v;
        }
      }
  }
}

extern "C" void kernel_launch(void* const* d_in, const int* in_sizes, int n_in,
                              void* d_out, int out_size, void* d_ws, size_t ws_size,
                              hipStream_t stream) {
  const float* x     = (const float*)d_in[0];
  const float* w_off = (const float*)d_in[1];
  const float* b_off = (const float*)d_in[2];
  const float* w_def = (const float*)d_in[3];
  const float* b_def = (const float*)d_in[4];
  const float* ln_w  = (const float*)d_in[5];
  const float* ln_b  = (const float*)d_in[6];
  const float* w_dw  = (const float*)d_in[7];
  const float* b_dw  = (const float*)d_in[8];
  const float* w_pw  = (const float*)d_in[9];
  const float* b_pw  = (const float*)d_in[10];
  float* out = (float*)d_out;

  hipLaunchKernelGGL(k_prep, dim3(784), dim3(256), 0, stream, w_def, w_pw, w_off);
  hipLaunchKernelGGL(k_fused, dim3(BN * HN * 3), dim3(256), 0, stream,
                     x, b_off, b_def, ln_w, ln_b, w_dw, b_dw, b_pw, out);
}